// Round 1
// 346.556 us; speedup vs baseline: 1.1863x; 1.1863x over previous
//
#include <hip/hip_runtime.h>
#include <hip/hip_bf16.h>
#include <stdint.h>

typedef __bf16 bf16;
typedef __attribute__((ext_vector_type(8))) __bf16 bf16x8;
typedef __attribute__((ext_vector_type(4))) float f32x4;

static constexpr int kTok = 4096;    // B*S
static constexpr int kHid = 1024;
static constexpr int kInter = 4096;

// async global->LDS, 16B/lane. LDS arg must be wave-uniform base; HW adds
// lane*16. Global arg is per-lane. (cdna_hip_programming.md §5)
#define GLDS16(g, l)                                                \
  __builtin_amdgcn_global_load_lds(                                 \
      (const __attribute__((address_space(1))) void*)(g),           \
      (__attribute__((address_space(3))) void*)(l), 16, 0, 0)

// ---------------- fp32 -> bf16 one-shot convert of all GEMM operands ------
// blockIdx.y: 0=X 1=Wg 2=Wu 3=Wd 4=Wr. 8 elems/thread, 16B stores.
__global__ void __launch_bounds__(256) k_cvt_all(
    const float* X, const float* Wg, const float* Wu, const float* Wd,
    const float* Wr, bf16* Xb, bf16* Wgb, bf16* Wub, bf16* Wdb, bf16* Wrb) {
  const float* src;
  bf16* dst;
  long n;
  switch (blockIdx.y) {
    case 0: src = X;  dst = Xb;  n = (long)kTok * kHid;   break;
    case 1: src = Wg; dst = Wgb; n = (long)kInter * kHid; break;
    case 2: src = Wu; dst = Wub; n = (long)kInter * kHid; break;
    case 3: src = Wd; dst = Wdb; n = (long)kHid * kInter; break;
    default: src = Wr; dst = Wrb; n = 128L * kHid;        break;
  }
  const long i = ((long)blockIdx.x * 256 + threadIdx.x) * 8;
  if (i >= n) return;
  const f32x4 a = *(const f32x4*)(src + i);
  const f32x4 b = *(const f32x4*)(src + i + 4);
  bf16x8 o;
#pragma unroll
  for (int k = 0; k < 4; ++k) { o[k] = (bf16)a[k]; o[4 + k] = (bf16)b[k]; }
  *(bf16x8*)(dst + i) = o;
}

// ---------------- router GEMM (bf16, global_load_lds, split-K=4) ----------
// out1(4096x128) += Xb(4096x1024) * Wrb(128x1024)^T over K-quarter z.
__global__ void __launch_bounds__(256, 2) gemm_router(
    const bf16* A, const bf16* Bm, float* outF) {
  constexpr int K = kHid, N = 128;
  __shared__ bf16 sA[128 * 32];
  __shared__ bf16 sB[128 * 32];
  const int t = threadIdx.x;
  const int w = t >> 6;
  const int L = t & 63;
  const long m0 = (long)blockIdx.y * 128;
  const int zb = blockIdx.z * 256;  // K-quarter base
  const int wm = (w >> 1) * 64;
  const int wn = (w & 1) * 64;

  f32x4 acc[4][4];
  const f32x4 fzero = {0.f, 0.f, 0.f, 0.f};
#pragma unroll
  for (int i = 0; i < 4; ++i)
#pragma unroll
    for (int j = 0; j < 4; ++j) acc[i][j] = fzero;

  // staging: call c covers rows c*64 + (t>>2), 8 cols at (t&3)*8
  const int r0 = t >> 2;
  const int ko = (t & 3) * 8;
  const bf16* gA0 = A + (m0 + r0) * K + zb + ko;
  const bf16* gA1 = gA0 + (long)64 * K;
  const bf16* gB0 = Bm + (long)r0 * K + zb + ko;
  const bf16* gB1 = gB0 + (long)64 * K;
  bf16* lA0 = sA + w * 512;          // wave-uniform LDS bases
  bf16* lA1 = sA + 2048 + w * 512;
  bf16* lB0 = sB + w * 512;
  bf16* lB1 = sB + 2048 + w * 512;

  const int la = L & 15;
  const int lk = (L >> 4) * 8;
  const bf16* sAr = sA + (wm + la) * 32 + lk;
  const bf16* sBr = sB + (wn + la) * 32 + lk;

  for (int kt = 0; kt < 8; ++kt) {
    const int k0 = kt << 5;
    GLDS16(gA0 + k0, lA0);
    GLDS16(gA1 + k0, lA1);
    GLDS16(gB0 + k0, lB0);
    GLDS16(gB1 + k0, lB1);
    __syncthreads();  // drains vmcnt -> tiles resident
    bf16x8 af[4], bfm[4];
#pragma unroll
    for (int i = 0; i < 4; ++i) {
      af[i] = *(const bf16x8*)(sAr + i * 16 * 32);
      bfm[i] = *(const bf16x8*)(sBr + i * 16 * 32);
    }
#pragma unroll
    for (int i = 0; i < 4; ++i)
#pragma unroll
      for (int j = 0; j < 4; ++j)
        acc[i][j] = __builtin_amdgcn_mfma_f32_16x16x32_bf16(af[i], bfm[j],
                                                            acc[i][j], 0, 0, 0);
    __syncthreads();  // all waves done reading before next overwrite
  }
  const long col0 = wn + la;
  const long row0 = m0 + wm + (L >> 4) * 4;
#pragma unroll
  for (int i = 0; i < 4; ++i)
#pragma unroll
    for (int j = 0; j < 4; ++j)
#pragma unroll
      for (int r = 0; r < 4; ++r)
        __hip_atomic_fetch_add(&outF[(row0 + i * 16 + r) * N + col0 + j * 16],
                               acc[i][j][r], __ATOMIC_RELAXED,
                               __HIP_MEMORY_SCOPE_AGENT);
}

// ---------------- fused gate+up+silu (bf16, global_load_lds) --------------
// H(4096x4096) = silu(Xb*Wgb^T) * (Xb*Wub^T), bf16 out to ws.
__global__ void __launch_bounds__(256, 2) gemm_gu(
    const bf16* X, const bf16* Wg, const bf16* Wu, bf16* H) {
  constexpr int K = kHid, N = kInter;
  __shared__ bf16 sX[128 * 32];
  __shared__ bf16 sG[128 * 32];
  __shared__ bf16 sU[128 * 32];
  const int t = threadIdx.x;
  const int w = t >> 6;
  const int L = t & 63;
  const long m0 = (long)blockIdx.y * 128;
  const long n0 = (long)blockIdx.x * 128;
  const int wm = (w >> 1) * 64;
  const int wn = (w & 1) * 64;

  f32x4 accG[4][4], accU[4][4];
  const f32x4 fzero = {0.f, 0.f, 0.f, 0.f};
#pragma unroll
  for (int i = 0; i < 4; ++i)
#pragma unroll
    for (int j = 0; j < 4; ++j) { accG[i][j] = fzero; accU[i][j] = fzero; }

  const int r0 = t >> 2;
  const int ko = (t & 3) * 8;
  const bf16* gX0 = X + (m0 + r0) * K + ko;
  const bf16* gX1 = gX0 + (long)64 * K;
  const bf16* gG0 = Wg + (n0 + r0) * K + ko;
  const bf16* gG1 = gG0 + (long)64 * K;
  const bf16* gU0 = Wu + (n0 + r0) * K + ko;
  const bf16* gU1 = gU0 + (long)64 * K;
  bf16* lX0 = sX + w * 512;
  bf16* lX1 = sX + 2048 + w * 512;
  bf16* lG0 = sG + w * 512;
  bf16* lG1 = sG + 2048 + w * 512;
  bf16* lU0 = sU + w * 512;
  bf16* lU1 = sU + 2048 + w * 512;

  const int la = L & 15;
  const int lk = (L >> 4) * 8;
  const bf16* sXr = sX + (wm + la) * 32 + lk;
  const bf16* sGr = sG + (wn + la) * 32 + lk;
  const bf16* sUr = sU + (wn + la) * 32 + lk;

  for (int kt = 0; kt < K / 32; ++kt) {
    const int k0 = kt << 5;
    GLDS16(gX0 + k0, lX0);
    GLDS16(gX1 + k0, lX1);
    GLDS16(gG0 + k0, lG0);
    GLDS16(gG1 + k0, lG1);
    GLDS16(gU0 + k0, lU0);
    GLDS16(gU1 + k0, lU1);
    __syncthreads();
    bf16x8 af[4], bg[4], bu[4];
#pragma unroll
    for (int i = 0; i < 4; ++i) {
      af[i] = *(const bf16x8*)(sXr + i * 16 * 32);
      bg[i] = *(const bf16x8*)(sGr + i * 16 * 32);
      bu[i] = *(const bf16x8*)(sUr + i * 16 * 32);
    }
#pragma unroll
    for (int i = 0; i < 4; ++i)
#pragma unroll
      for (int j = 0; j < 4; ++j) {
        accG[i][j] = __builtin_amdgcn_mfma_f32_16x16x32_bf16(af[i], bg[j],
                                                             accG[i][j], 0, 0, 0);
        accU[i][j] = __builtin_amdgcn_mfma_f32_16x16x32_bf16(af[i], bu[j],
                                                             accU[i][j], 0, 0, 0);
      }
    __syncthreads();
  }
  const long col0 = n0 + wn + la;
  const long row0 = m0 + wm + (L >> 4) * 4;
#pragma unroll
  for (int i = 0; i < 4; ++i)
#pragma unroll
    for (int j = 0; j < 4; ++j)
#pragma unroll
      for (int r = 0; r < 4; ++r) {
        const float g = accG[i][j][r];
        const float u = accU[i][j][r];
        H[(row0 + i * 16 + r) * N + col0 + j * 16] =
            (bf16)(g / (1.f + __expf(-g)) * u);
      }
}

// ---------------- down GEMM (bf16 both sides, split-K=2, atomic acc) ------
// out0(4096x1024) += H(4096x4096,bf16) * Wdb(1024x4096)^T over K-half z.
__global__ void __launch_bounds__(256, 2) gemm_down(
    const bf16* Hs, const bf16* Wd, float* out0) {
  constexpr int K = kInter, N = kHid;
  __shared__ bf16 sA[128 * 32];
  __shared__ bf16 sB[128 * 32];
  const int t = threadIdx.x;
  const int w = t >> 6;
  const int L = t & 63;
  const long m0 = (long)blockIdx.y * 128;
  const long n0 = (long)blockIdx.x * 128;
  const long zb = (long)blockIdx.z * 2048;  // K-half base
  const int wm = (w >> 1) * 64;
  const int wn = (w & 1) * 64;

  f32x4 acc[4][4];
  const f32x4 fzero = {0.f, 0.f, 0.f, 0.f};
#pragma unroll
  for (int i = 0; i < 4; ++i)
#pragma unroll
    for (int j = 0; j < 4; ++j) acc[i][j] = fzero;

  const int r0 = t >> 2;
  const int ko = (t & 3) * 8;
  const bf16* gA0 = Hs + (m0 + r0) * K + zb + ko;
  const bf16* gA1 = gA0 + (long)64 * K;
  const bf16* gB0 = Wd + (n0 + r0) * K + zb + ko;
  const bf16* gB1 = gB0 + (long)64 * K;
  bf16* lA0 = sA + w * 512;
  bf16* lA1 = sA + 2048 + w * 512;
  bf16* lB0 = sB + w * 512;
  bf16* lB1 = sB + 2048 + w * 512;

  const int la = L & 15;
  const int lk = (L >> 4) * 8;
  const bf16* sAr = sA + (wm + la) * 32 + lk;
  const bf16* sBr = sB + (wn + la) * 32 + lk;

  for (int kt = 0; kt < 64; ++kt) {
    const int k0 = kt << 5;
    GLDS16(gA0 + k0, lA0);
    GLDS16(gA1 + k0, lA1);
    GLDS16(gB0 + k0, lB0);
    GLDS16(gB1 + k0, lB1);
    __syncthreads();
    bf16x8 af[4], bfm[4];
#pragma unroll
    for (int i = 0; i < 4; ++i) {
      af[i] = *(const bf16x8*)(sAr + i * 16 * 32);
      bfm[i] = *(const bf16x8*)(sBr + i * 16 * 32);
    }
#pragma unroll
    for (int i = 0; i < 4; ++i)
#pragma unroll
      for (int j = 0; j < 4; ++j)
        acc[i][j] = __builtin_amdgcn_mfma_f32_16x16x32_bf16(af[i], bfm[j],
                                                            acc[i][j], 0, 0, 0);
    __syncthreads();
  }
  const long col0 = n0 + wn + la;
  const long row0 = m0 + wm + (L >> 4) * 4;
#pragma unroll
  for (int i = 0; i < 4; ++i)
#pragma unroll
    for (int j = 0; j < 4; ++j)
#pragma unroll
      for (int r = 0; r < 4; ++r)
        __hip_atomic_fetch_add(
            &out0[(row0 + i * 16 + r) * N + col0 + j * 16], acc[i][j][r],
            __ATOMIC_RELAXED, __HIP_MEMORY_SCOPE_AGENT);
}

__global__ void k_zero4(float* p) {
  const long i = ((long)blockIdx.x * 256 + threadIdx.x) * 4;
  const f32x4 z = {0.f, 0.f, 0.f, 0.f};
  *(f32x4*)(p + i) = z;
}

// ---------------- routing + experts (unchanged) ----------------
__global__ void __launch_bounds__(256) route_expert(
    const float* logits, const float* X, const float* dE, const float* uE,
    float* out0) {
  __shared__ float s_vals[4][128];
  __shared__ int s_idx[4][128];
  const int w = threadIdx.x >> 6;
  const int L = threadIdx.x & 63;
  const int j = blockIdx.x * 4 + w;

  const int half = (j & 1) * 64;
  const int rx = j >> 1;
  const float vx = logits[(long)rx * 128 + half + L];
  const float vy = logits[(long)(2048 + rx) * 128 + half + L];

  int rkx = 0, rky = 0;
  for (int m = 0; m < 64; ++m) {
    const float mx = __shfl(vx, m);
    const float my = __shfl(vy, m);
    rkx += (mx > vx) || (mx == vx && m < L);
    rky += (my > vy) || (my == vy && m < L);
  }
  rkx &= 63;
  rky &= 63;
  s_vals[w][rkx] = vx;
  s_idx[w][rkx] = L;
  s_vals[w][64 + rky] = vy;
  s_idx[w][64 + rky] = L;
  __syncthreads();

  int p = 0, q = 0;
  const bool valid = (L < 20);
  if (L < 8)       { p = L;      q = 0; }
  else if (L < 12) { p = L - 8;  q = 1; }
  else if (L < 14) { p = L - 12; q = 2; }
  else if (L < 16) { p = L - 14; q = 3; }
  else if (L < 20) { p = 0;      q = L - 12; }
  const float kNegBig = -3.0e38f;
  float myv = valid ? (s_vals[w][p] + s_vals[w][64 + q]) : kNegBig;
  int mypos = valid ? (p * 64 + q) : 0x7fffffff;

  float topv[8];
  int tope[8];
#pragma unroll
  for (int r = 0; r < 8; ++r) {
    float bv = myv;
    int bp = mypos;
#pragma unroll
    for (int d = 32; d > 0; d >>= 1) {
      const float ov = __shfl_xor(bv, d);
      const int op = __shfl_xor(bp, d);
      if (ov > bv || (ov == bv && op < bp)) { bv = ov; bp = op; }
    }
    topv[r] = bv;
    const int pp = (bp >> 6) & 127, qq = bp & 63;
    tope[r] = (s_idx[w][pp] * 64 + s_idx[w][64 + qq]) & 4095;
    if (mypos == bp) myv = kNegBig;
  }

  float e[8], wsum = 0.f;
#pragma unroll
  for (int r = 0; r < 8; ++r) {
    e[r] = __expf(topv[r] - topv[0]);
    wsum += e[r];
  }
  const float winv = 1.f / wsum;

  const long xoff = (long)j * kHid + L * 16;
  float xv[16], acc[16];
#pragma unroll
  for (int v4 = 0; v4 < 4; ++v4) {
    const f32x4 xl = *(const f32x4*)(X + xoff + v4 * 4);
#pragma unroll
    for (int i = 0; i < 4; ++i) { xv[v4 * 4 + i] = xl[i]; acc[v4 * 4 + i] = 0.f; }
  }

  for (int r = 0; r < 8; ++r) {
    const long eo = (long)tope[r] * kHid + L * 16;
    float d = 0.f;
#pragma unroll
    for (int v4 = 0; v4 < 4; ++v4) {
      const f32x4 dl = *(const f32x4*)(dE + eo + v4 * 4);
#pragma unroll
      for (int i = 0; i < 4; ++i) d += dl[i] * xv[v4 * 4 + i];
    }
#pragma unroll
    for (int dd = 32; dd > 0; dd >>= 1) d += __shfl_xor(d, dd);
    const float ew = d / (1.f + __expf(-d)) * (e[r] * winv);
#pragma unroll
    for (int v4 = 0; v4 < 4; ++v4) {
      const f32x4 ul = *(const f32x4*)(uE + eo + v4 * 4);
#pragma unroll
      for (int i = 0; i < 4; ++i) acc[v4 * 4 + i] += ew * ul[i];
    }
  }

  float* po = out0 + xoff;
#pragma unroll
  for (int v4 = 0; v4 < 4; ++v4) {
    f32x4 ov = *(const f32x4*)(po + v4 * 4);
#pragma unroll
    for (int i = 0; i < 4; ++i) ov[i] += acc[v4 * 4 + i];
    *(f32x4*)(po + v4 * 4) = ov;
  }
}

extern "C" void kernel_launch(void* const* d_in, const int* in_sizes, int n_in,
                              void* d_out, int out_size, void* d_ws,
                              size_t ws_size, hipStream_t stream) {
  (void)in_sizes; (void)n_in; (void)out_size; (void)ws_size;
  const float* X  = (const float*)d_in[0];
  const float* Wg = (const float*)d_in[1];
  const float* Wu = (const float*)d_in[2];
  const float* Wd = (const float*)d_in[3];
  const float* Wr = (const float*)d_in[4];
  const float* dE = (const float*)d_in[5];
  const float* uE = (const float*)d_in[6];

  float* out0 = (float*)d_out;                  // (4096,1024) final
  float* out1 = out0 + (size_t)kTok * kHid;     // (2,4096,64) router logits

  // workspace layout (64 MiB total):
  //   wsH  : 32 MiB  H bf16 (Wrb aliased at its head; router runs before gu)
  //   Xb   :  8 MiB  X bf16
  //   Wgb  :  8 MiB  Wg bf16
  //   Wub  :  8 MiB  Wu bf16
  //   Wdb  :  8 MiB  Wd bf16
  bf16* wsH = (bf16*)d_ws;
  bf16* Wrb = wsH;  // 128*1024 bf16, consumed by router, then overwritten by H
  bf16* Xb  = wsH + (size_t)kTok * kInter;
  bf16* Wgb = Xb  + (size_t)kTok * kHid;
  bf16* Wub = Wgb + (size_t)kInter * kHid;
  bf16* Wdb = Wub + (size_t)kInter * kHid;

  dim3 blk(256);
  // zero out0 (16 MiB, split-K atomics) + out1 (2 MiB, router atomics)
  k_zero4<<<dim3((kTok * kHid + 2 * kTok * 64) / 1024), blk, 0, stream>>>(out0);
  // fp32 -> bf16 for all GEMM operands (one pass)
  k_cvt_all<<<dim3(2048, 5), blk, 0, stream>>>(X, Wg, Wu, Wd, Wr,
                                               Xb, Wgb, Wub, Wdb, Wrb);
  // router logits -> out1 (fp32, atomic split-K=4); route_expert reads them
  gemm_router<<<dim3(1, 32, 4), blk, 0, stream>>>(Xb, Wrb, out1);
  // H = silu(X*Wg^T) * (X*Wu^T) -> wsH, fused (overwrites Wrb region)
  gemm_gu<<<dim3(32, 32), blk, 0, stream>>>(Xb, Wgb, Wub, wsH);
  // out0 += H*Wd^T, split-K=2 (512 blocks, 2/CU)
  gemm_down<<<dim3(8, 32, 2), blk, 0, stream>>>(wsH, Wdb, out0);
  // routing + experts, RMW out0
  route_expert<<<dim3(kTok / 4), blk, 0, stream>>>(out1, X, dE, uE, out0);
}

// Round 3
// 345.057 us; speedup vs baseline: 1.1914x; 1.0043x over previous
//
#include <hip/hip_runtime.h>
#include <hip/hip_bf16.h>
#include <stdint.h>

typedef __bf16 bf16;
typedef __attribute__((ext_vector_type(8))) __bf16 bf16x8;
typedef __attribute__((ext_vector_type(4))) float f32x4;

static constexpr int kTok = 4096;    // B*S
static constexpr int kHid = 1024;
static constexpr int kInter = 4096;

// async global->LDS, 16B/lane. LDS arg must be wave-uniform base; HW adds
// lane*16. Global arg is per-lane.
#define GLDS16(g, l)                                                \
  __builtin_amdgcn_global_load_lds(                                 \
      (const __attribute__((address_space(1))) void*)(g),           \
      (__attribute__((address_space(3))) void*)(l), 16, 0, 0)

// counted-vmcnt wait + raw barrier. Wait FIRST (own loads resident), then
// barrier (all waves' loads resident). Never vmcnt(0) in steady state;
// peeled tail iterations drain ...->4->0 (m201 pattern).
#define WAIT_BAR(N)                                     \
  asm volatile("s_waitcnt vmcnt(" #N ")" ::: "memory"); \
  __builtin_amdgcn_s_barrier();                         \
  __builtin_amdgcn_sched_barrier(0)

// ---------------- fp32 -> bf16 convert of all GEMM operands + zero-out ----
// blockIdx.y: 0=X 1=Wg 2=Wu 3=Wd 4=Wr 5=zero(out0+out1)
__global__ void __launch_bounds__(256) k_cvt_all(
    const float* X, const float* Wg, const float* Wu, const float* Wd,
    const float* Wr, bf16* Xb, bf16* Wgb, bf16* Wub, bf16* Wdb, bf16* Wrb,
    float* out0) {
  const long i = ((long)blockIdx.x * 256 + threadIdx.x) * 8;
  if (blockIdx.y == 5) {  // zero out0 (4M) + out1 (512K) floats
    if (i < (long)kTok * kHid + 2L * kTok * 64) {
      const f32x4 z = {0.f, 0.f, 0.f, 0.f};
      *(f32x4*)(out0 + i) = z;
      *(f32x4*)(out0 + i + 4) = z;
    }
    return;
  }
  const float* src;
  bf16* dst;
  long n;
  switch (blockIdx.y) {
    case 0: src = X;  dst = Xb;  n = (long)kTok * kHid;   break;
    case 1: src = Wg; dst = Wgb; n = (long)kInter * kHid; break;
    case 2: src = Wu; dst = Wub; n = (long)kInter * kHid; break;
    case 3: src = Wd; dst = Wdb; n = (long)kHid * kInter; break;
    default: src = Wr; dst = Wrb; n = 128L * kHid;        break;
  }
  if (i >= n) return;
  const f32x4 a = *(const f32x4*)(src + i);
  const f32x4 b = *(const f32x4*)(src + i + 4);
  bf16x8 o;
#pragma unroll
  for (int k = 0; k < 4; ++k) { o[k] = (bf16)a[k]; o[4 + k] = (bf16)b[k]; }
  *(bf16x8*)(dst + i) = o;
}

// ---------------- router GEMM (bf16, 4-buf pipeline, split-K=4) -----------
// out1(4096x128) += Xb(4096x1024) * Wrb(128x1024)^T over K-quarter z.
__global__ void __launch_bounds__(256, 2) gemm_router(
    const bf16* A, const bf16* Bm, float* outF) {
  constexpr int K = kHid, N = 128;
  constexpr int NT = 8;  // 256 K / 32
  __shared__ bf16 sA[4][128 * 32];
  __shared__ bf16 sB[4][128 * 32];
  const int t = threadIdx.x;
  const int w = t >> 6;
  const int L = t & 63;
  const long m0 = (long)blockIdx.y * 128;
  const int zb = blockIdx.z * 256;
  const int wm = (w >> 1) * 64;
  const int wn = (w & 1) * 64;

  f32x4 acc[4][4];
  const f32x4 fzero = {0.f, 0.f, 0.f, 0.f};
#pragma unroll
  for (int i = 0; i < 4; ++i)
#pragma unroll
    for (int j = 0; j < 4; ++j) acc[i][j] = fzero;

  const int r0 = t >> 2;
  const int ko = (t & 3) * 8;
  const bf16* gA0 = A + (m0 + r0) * K + zb + ko;
  const bf16* gA1 = gA0 + (long)64 * K;
  const bf16* gB0 = Bm + (long)r0 * K + zb + ko;
  const bf16* gB1 = gB0 + (long)64 * K;
  const int lo = w * 512;

#define STAGE_R(b_, tt)                          \
  {                                              \
    const long kk_ = (long)(tt) << 5;            \
    GLDS16(gA0 + kk_, &sA[b_][lo]);              \
    GLDS16(gA1 + kk_, &sA[b_][2048 + lo]);       \
    GLDS16(gB0 + kk_, &sB[b_][lo]);              \
    GLDS16(gB1 + kk_, &sB[b_][2048 + lo]);       \
  }
  // depth-3 prologue: tiles 0,1,2 (12 outstanding)
  STAGE_R(0, 0); STAGE_R(1, 1); STAGE_R(2, 2);

  const int la = L & 15;
  const int lk = (L >> 4) * 8;
  const int roA = (wm + la) * 32 + lk;
  const int roB = (wn + la) * 32 + lk;

#define R_BODY(BUF)                                                         \
  {                                                                         \
    const bf16* pa = &sA[BUF][roA];                                         \
    const bf16* pb = &sB[BUF][roB];                                         \
    bf16x8 af[4], bfm[4];                                                   \
    _Pragma("unroll") for (int i = 0; i < 4; ++i) {                         \
      af[i] = *(const bf16x8*)(pa + i * 512);                               \
      bfm[i] = *(const bf16x8*)(pb + i * 512);                              \
    }                                                                       \
    __builtin_amdgcn_s_setprio(1);                                          \
    _Pragma("unroll") for (int i = 0; i < 4; ++i)                           \
      _Pragma("unroll") for (int j = 0; j < 4; ++j)                         \
        acc[i][j] = __builtin_amdgcn_mfma_f32_16x16x32_bf16(                \
            af[i], bfm[j], acc[i][j], 0, 0, 0);                             \
    __builtin_amdgcn_s_setprio(0);                                          \
  }

  // main: invariant before wait = 12 outstanding (tiles kt..kt+2)
  for (int kt = 0; kt < NT - 2; ++kt) {
    WAIT_BAR(8);  // tile kt resident
    if (kt + 3 < NT) STAGE_R((kt + 3) & 3, kt + 3);
    R_BODY(kt & 3);
  }
  WAIT_BAR(4);  // tile NT-2 resident (8 outstanding before wait)
  R_BODY((NT - 2) & 3);
  WAIT_BAR(0);  // tile NT-1 resident, drained
  R_BODY((NT - 1) & 3);

  const long col0 = wn + la;
  const long row0 = m0 + wm + (L >> 4) * 4;
#pragma unroll
  for (int i = 0; i < 4; ++i)
#pragma unroll
    for (int j = 0; j < 4; ++j)
#pragma unroll
      for (int r = 0; r < 4; ++r)
        __hip_atomic_fetch_add(&outF[(row0 + i * 16 + r) * N + col0 + j * 16],
                               acc[i][j][r], __ATOMIC_RELAXED,
                               __HIP_MEMORY_SCOPE_AGENT);
}

// ---------------- fused gate+up+silu (bf16, 3-buf pipeline) ---------------
// H(4096x4096) = silu(Xb*Wgb^T) * (Xb*Wub^T), bf16 out to ws.
__global__ void __launch_bounds__(256, 2) gemm_gu(
    const bf16* X, const bf16* Wg, const bf16* Wu, bf16* H) {
  constexpr int K = kHid, N = kInter;
  constexpr int NT = K / 32;  // 32
  __shared__ bf16 sX[3][128 * 32];
  __shared__ bf16 sG[3][128 * 32];
  __shared__ bf16 sU[3][128 * 32];
  const int t = threadIdx.x;
  const int w = t >> 6;
  const int L = t & 63;
  const long m0 = (long)blockIdx.y * 128;
  const long n0 = (long)blockIdx.x * 128;
  const int wm = (w >> 1) * 64;
  const int wn = (w & 1) * 64;

  f32x4 accG[4][4], accU[4][4];
  const f32x4 fzero = {0.f, 0.f, 0.f, 0.f};
#pragma unroll
  for (int i = 0; i < 4; ++i)
#pragma unroll
    for (int j = 0; j < 4; ++j) { accG[i][j] = fzero; accU[i][j] = fzero; }

  const int r0 = t >> 2;
  const int ko = (t & 3) * 8;
  const bf16* gX0 = X + (m0 + r0) * K + ko;
  const bf16* gX1 = gX0 + (long)64 * K;
  const bf16* gG0 = Wg + (n0 + r0) * K + ko;
  const bf16* gG1 = gG0 + (long)64 * K;
  const bf16* gU0 = Wu + (n0 + r0) * K + ko;
  const bf16* gU1 = gU0 + (long)64 * K;
  const int lo = w * 512;

#define STAGE_GU(b_, tt)                         \
  {                                              \
    const long kk_ = (long)(tt) << 5;            \
    GLDS16(gX0 + kk_, &sX[b_][lo]);              \
    GLDS16(gX1 + kk_, &sX[b_][2048 + lo]);       \
    GLDS16(gG0 + kk_, &sG[b_][lo]);              \
    GLDS16(gG1 + kk_, &sG[b_][2048 + lo]);       \
    GLDS16(gU0 + kk_, &sU[b_][lo]);              \
    GLDS16(gU1 + kk_, &sU[b_][2048 + lo]);       \
  }
  // depth-2 prologue: tiles 0,1 (12 outstanding)
  STAGE_GU(0, 0); STAGE_GU(1, 1);

  const int la = L & 15;
  const int lk = (L >> 4) * 8;
  const int roX = (wm + la) * 32 + lk;
  const int roW = (wn + la) * 32 + lk;

#define GU_BODY(BUF)                                                        \
  {                                                                         \
    const bf16* px = &sX[BUF][roX];                                         \
    const bf16* pg = &sG[BUF][roW];                                         \
    const bf16* pu = &sU[BUF][roW];                                         \
    bf16x8 af[4], bg[4], bu[4];                                             \
    _Pragma("unroll") for (int i = 0; i < 4; ++i) {                         \
      af[i] = *(const bf16x8*)(px + i * 512);                               \
      bg[i] = *(const bf16x8*)(pg + i * 512);                               \
      bu[i] = *(const bf16x8*)(pu + i * 512);                               \
    }                                                                       \
    __builtin_amdgcn_s_setprio(1);                                          \
    _Pragma("unroll") for (int i = 0; i < 4; ++i)                           \
      _Pragma("unroll") for (int j = 0; j < 4; ++j) {                       \
        accG[i][j] = __builtin_amdgcn_mfma_f32_16x16x32_bf16(               \
            af[i], bg[j], accG[i][j], 0, 0, 0);                             \
        accU[i][j] = __builtin_amdgcn_mfma_f32_16x16x32_bf16(               \
            af[i], bu[j], accU[i][j], 0, 0, 0);                             \
      }                                                                     \
    __builtin_amdgcn_s_setprio(0);                                          \
  }

  // main: invariant before wait = 12 outstanding (tiles kt, kt+1)
  int cur = 0;
  for (int kt = 0; kt < NT - 1; ++kt) {
    WAIT_BAR(6);  // tile kt resident
    const int stg = (cur == 0) ? 2 : cur - 1;  // buffer of tile kt-1 (consumed)
    if (kt + 2 < NT) STAGE_GU(stg, kt + 2);
    GU_BODY(cur);
    cur = (cur == 2) ? 0 : cur + 1;
  }
  WAIT_BAR(0);  // final tile resident, drained
  GU_BODY(cur);

  const long col0 = n0 + wn + la;
  const long row0 = m0 + wm + (L >> 4) * 4;
#pragma unroll
  for (int i = 0; i < 4; ++i)
#pragma unroll
    for (int j = 0; j < 4; ++j)
#pragma unroll
      for (int r = 0; r < 4; ++r) {
        const float g = accG[i][j][r];
        const float u = accU[i][j][r];
        H[(row0 + i * 16 + r) * N + col0 + j * 16] =
            (bf16)(g / (1.f + __expf(-g)) * u);
      }
}

// ---------------- down GEMM (bf16, 4-buf pipeline, split-K=2) -------------
// out0(4096x1024) += H(4096x4096,bf16) * Wdb(1024x4096)^T over K-half z.
__global__ void __launch_bounds__(256, 2) gemm_down(
    const bf16* Hs, const bf16* Wd, float* out0) {
  constexpr int K = kInter, N = kHid;
  constexpr int NT = 64;  // 2048 K-half / 32
  __shared__ bf16 sA[4][128 * 32];
  __shared__ bf16 sB[4][128 * 32];
  const int t = threadIdx.x;
  const int w = t >> 6;
  const int L = t & 63;
  const long m0 = (long)blockIdx.y * 128;
  const long n0 = (long)blockIdx.x * 128;
  const long zb = (long)blockIdx.z * 2048;
  const int wm = (w >> 1) * 64;
  const int wn = (w & 1) * 64;

  f32x4 acc[4][4];
  const f32x4 fzero = {0.f, 0.f, 0.f, 0.f};
#pragma unroll
  for (int i = 0; i < 4; ++i)
#pragma unroll
    for (int j = 0; j < 4; ++j) acc[i][j] = fzero;

  const int r0 = t >> 2;
  const int ko = (t & 3) * 8;
  const bf16* gA0 = Hs + (m0 + r0) * K + zb + ko;
  const bf16* gA1 = gA0 + (long)64 * K;
  const bf16* gB0 = Wd + (n0 + r0) * K + zb + ko;
  const bf16* gB1 = gB0 + (long)64 * K;
  const int lo = w * 512;

#define STAGE_D(b_, tt)                          \
  {                                              \
    const long kk_ = (long)(tt) << 5;            \
    GLDS16(gA0 + kk_, &sA[b_][lo]);              \
    GLDS16(gA1 + kk_, &sA[b_][2048 + lo]);       \
    GLDS16(gB0 + kk_, &sB[b_][lo]);              \
    GLDS16(gB1 + kk_, &sB[b_][2048 + lo]);       \
  }
  // depth-3 prologue: tiles 0,1,2 (12 outstanding)
  STAGE_D(0, 0); STAGE_D(1, 1); STAGE_D(2, 2);

  const int la = L & 15;
  const int lk = (L >> 4) * 8;
  const int roA = (wm + la) * 32 + lk;
  const int roB = (wn + la) * 32 + lk;

#define D_BODY(BUF)                                                         \
  {                                                                         \
    const bf16* pa = &sA[BUF][roA];                                         \
    const bf16* pb = &sB[BUF][roB];                                         \
    bf16x8 af[4], bfm[4];                                                   \
    _Pragma("unroll") for (int i = 0; i < 4; ++i) {                         \
      af[i] = *(const bf16x8*)(pa + i * 512);                               \
      bfm[i] = *(const bf16x8*)(pb + i * 512);                              \
    }                                                                       \
    __builtin_amdgcn_s_setprio(1);                                          \
    _Pragma("unroll") for (int i = 0; i < 4; ++i)                           \
      _Pragma("unroll") for (int j = 0; j < 4; ++j)                         \
        acc[i][j] = __builtin_amdgcn_mfma_f32_16x16x32_bf16(                \
            af[i], bfm[j], acc[i][j], 0, 0, 0);                             \
    __builtin_amdgcn_s_setprio(0);                                          \
  }

  // main: invariant before wait = 12 outstanding (tiles kt..kt+2)
  for (int kt = 0; kt < NT - 2; ++kt) {
    WAIT_BAR(8);  // tile kt resident
    if (kt + 3 < NT) STAGE_D((kt + 3) & 3, kt + 3);
    D_BODY(kt & 3);
  }
  WAIT_BAR(4);  // tile NT-2 resident (8 outstanding before wait)
  D_BODY((NT - 2) & 3);
  WAIT_BAR(0);  // tile NT-1 resident, drained
  D_BODY((NT - 1) & 3);

  const long col0 = n0 + wn + la;
  const long row0 = m0 + wm + (L >> 4) * 4;
#pragma unroll
  for (int i = 0; i < 4; ++i)
#pragma unroll
    for (int j = 0; j < 4; ++j)
#pragma unroll
      for (int r = 0; r < 4; ++r)
        __hip_atomic_fetch_add(
            &out0[(row0 + i * 16 + r) * N + col0 + j * 16], acc[i][j][r],
            __ATOMIC_RELAXED, __HIP_MEMORY_SCOPE_AGENT);
}

// ---------------- routing + experts (unchanged) ----------------
__global__ void __launch_bounds__(256) route_expert(
    const float* logits, const float* X, const float* dE, const float* uE,
    float* out0) {
  __shared__ float s_vals[4][128];
  __shared__ int s_idx[4][128];
  const int w = threadIdx.x >> 6;
  const int L = threadIdx.x & 63;
  const int j = blockIdx.x * 4 + w;

  const int half = (j & 1) * 64;
  const int rx = j >> 1;
  const float vx = logits[(long)rx * 128 + half + L];
  const float vy = logits[(long)(2048 + rx) * 128 + half + L];

  int rkx = 0, rky = 0;
  for (int m = 0; m < 64; ++m) {
    const float mx = __shfl(vx, m);
    const float my = __shfl(vy, m);
    rkx += (mx > vx) || (mx == vx && m < L);
    rky += (my > vy) || (my == vy && m < L);
  }
  rkx &= 63;
  rky &= 63;
  s_vals[w][rkx] = vx;
  s_idx[w][rkx] = L;
  s_vals[w][64 + rky] = vy;
  s_idx[w][64 + rky] = L;
  __syncthreads();

  int p = 0, q = 0;
  const bool valid = (L < 20);
  if (L < 8)       { p = L;      q = 0; }
  else if (L < 12) { p = L - 8;  q = 1; }
  else if (L < 14) { p = L - 12; q = 2; }
  else if (L < 16) { p = L - 14; q = 3; }
  else if (L < 20) { p = 0;      q = L - 12; }
  const float kNegBig = -3.0e38f;
  float myv = valid ? (s_vals[w][p] + s_vals[w][64 + q]) : kNegBig;
  int mypos = valid ? (p * 64 + q) : 0x7fffffff;

  float topv[8];
  int tope[8];
#pragma unroll
  for (int r = 0; r < 8; ++r) {
    float bv = myv;
    int bp = mypos;
#pragma unroll
    for (int d = 32; d > 0; d >>= 1) {
      const float ov = __shfl_xor(bv, d);
      const int op = __shfl_xor(bp, d);
      if (ov > bv || (ov == bv && op < bp)) { bv = ov; bp = op; }
    }
    topv[r] = bv;
    const int pp = (bp >> 6) & 127, qq = bp & 63;
    tope[r] = (s_idx[w][pp] * 64 + s_idx[w][64 + qq]) & 4095;
    if (mypos == bp) myv = kNegBig;
  }

  float e[8], wsum = 0.f;
#pragma unroll
  for (int r = 0; r < 8; ++r) {
    e[r] = __expf(topv[r] - topv[0]);
    wsum += e[r];
  }
  const float winv = 1.f / wsum;

  const long xoff = (long)j * kHid + L * 16;
  float xv[16], acc[16];
#pragma unroll
  for (int v4 = 0; v4 < 4; ++v4) {
    const f32x4 xl = *(const f32x4*)(X + xoff + v4 * 4);
#pragma unroll
    for (int i = 0; i < 4; ++i) { xv[v4 * 4 + i] = xl[i]; acc[v4 * 4 + i] = 0.f; }
  }

  for (int r = 0; r < 8; ++r) {
    const long eo = (long)tope[r] * kHid + L * 16;
    float d = 0.f;
#pragma unroll
    for (int v4 = 0; v4 < 4; ++v4) {
      const f32x4 dl = *(const f32x4*)(dE + eo + v4 * 4);
#pragma unroll
      for (int i = 0; i < 4; ++i) d += dl[i] * xv[v4 * 4 + i];
    }
#pragma unroll
    for (int dd = 32; dd > 0; dd >>= 1) d += __shfl_xor(d, dd);
    const float ew = d / (1.f + __expf(-d)) * (e[r] * winv);
#pragma unroll
    for (int v4 = 0; v4 < 4; ++v4) {
      const f32x4 ul = *(const f32x4*)(uE + eo + v4 * 4);
#pragma unroll
      for (int i = 0; i < 4; ++i) acc[v4 * 4 + i] += ew * ul[i];
    }
  }

  float* po = out0 + xoff;
#pragma unroll
  for (int v4 = 0; v4 < 4; ++v4) {
    f32x4 ov = *(const f32x4*)(po + v4 * 4);
#pragma unroll
    for (int i = 0; i < 4; ++i) ov[i] += acc[v4 * 4 + i];
    *(f32x4*)(po + v4 * 4) = ov;
  }
}

extern "C" void kernel_launch(void* const* d_in, const int* in_sizes, int n_in,
                              void* d_out, int out_size, void* d_ws,
                              size_t ws_size, hipStream_t stream) {
  (void)in_sizes; (void)n_in; (void)out_size; (void)ws_size;
  const float* X  = (const float*)d_in[0];
  const float* Wg = (const float*)d_in[1];
  const float* Wu = (const float*)d_in[2];
  const float* Wd = (const float*)d_in[3];
  const float* Wr = (const float*)d_in[4];
  const float* dE = (const float*)d_in[5];
  const float* uE = (const float*)d_in[6];

  float* out0 = (float*)d_out;                  // (4096,1024) final
  float* out1 = out0 + (size_t)kTok * kHid;     // (2,4096,64) router logits

  // workspace layout (64 MiB):
  //   wsH : 32 MiB H bf16 (Wrb aliased at head; router runs before gu)
  //   Xb/Wgb/Wub/Wdb : 8 MiB each
  bf16* wsH = (bf16*)d_ws;
  bf16* Wrb = wsH;
  bf16* Xb  = wsH + (size_t)kTok * kInter;
  bf16* Wgb = Xb  + (size_t)kTok * kHid;
  bf16* Wub = Wgb + (size_t)kInter * kHid;
  bf16* Wdb = Wub + (size_t)kInter * kHid;

  dim3 blk(256);
  // convert all operands + zero out0/out1, one launch
  k_cvt_all<<<dim3(2304, 6), blk, 0, stream>>>(X, Wg, Wu, Wd, Wr,
                                               Xb, Wgb, Wub, Wdb, Wrb, out0);
  // router logits -> out1 (fp32, atomic split-K=4)
  gemm_router<<<dim3(1, 32, 4), blk, 0, stream>>>(Xb, Wrb, out1);
  // H = silu(X*Wg^T) * (X*Wu^T) -> wsH
  gemm_gu<<<dim3(32, 32), blk, 0, stream>>>(Xb, Wgb, Wub, wsH);
  // out0 += H*Wd^T, split-K=2
  gemm_down<<<dim3(8, 32, 2), blk, 0, stream>>>(wsH, Wdb, out0);
  // routing + experts, RMW out0
  route_expert<<<dim3(kTok / 4), blk, 0, stream>>>(out1, X, dE, uE, out0);
}